// Round 5
// baseline (257.222 us; speedup 1.0000x reference)
//
#include <hip/hip_runtime.h>
#include <math.h>

constexpr int CIN      = 256;
constexpr int HW       = 16384;       // 128*128
constexpr int NMID     = 64;
constexpr int HWTILE   = 128;         // spatial positions per block (4 waves x 32)
constexpr int TILE_B   = 8192;        // padded A-tile image (80 rows x 80B)
constexpr int PSTRIDE  = 132;         // pout row stride (pad: 2-way banks = free)
constexpr int NORM_OFF = 512;         // mask (8*64) floats first
constexpr int K_OFF    = 75497984;    // 512 + 8*64*9*16384
constexpr int IDX_OFF  = 75497985;

typedef __attribute__((ext_vector_type(8))) short bf16x8;   // 8 bf16 = 4 VGPR
typedef __attribute__((ext_vector_type(4))) float f32x4;

__device__ __forceinline__ unsigned bf16_rne(float f) {
    unsigned u = __float_as_uint(f);
    return (u + 0x7fffu + ((u >> 16) & 1u)) >> 16;          // bf16 bits, RNE
}

__device__ __forceinline__ void gload_lds16(const void* gsrc, void* ldst) {
    __builtin_amdgcn_global_load_lds(
        (const __attribute__((address_space(1))) void*)gsrc,
        (__attribute__((address_space(3))) void*)ldst, 16, 0, 0);
}

// ---------------------------------------------------------------------------
// Repack W into MFMA A-fragment image, split bf16 hi/lo, with a row permutation
// chosen so each mid's 10 rows (score + 9 taps) land in ONE lane's D-fragments:
// D row-in-block = q*4+reg  =>  position p = (idx/4)*16 + q*4 + idx%4, where
// q = (mid&7)>>1, idx = (mid&1)*10 + j.  Tile (g*8+kc, part): 80 rows x 32 c.
__global__ __launch_bounds__(256) void prep_w(const float* __restrict__ Wm,
                                              char* __restrict__ ws)
{
    const int o = blockIdx.x;         // original W row 0..639
    const int c = threadIdx.x;        // 0..255
    int mid, j;
    if (o < NMID) { mid = o; j = 0; }
    else          { mid = (o - NMID) / 9; j = 1 + (o - NMID) % 9; }
    const int g  = mid >> 3, ml = mid & 7, q = ml >> 1, mi = ml & 1;
    const int idx = mi * 10 + j;
    const int p   = (idx >> 2) * 16 + q * 4 + (idx & 3);    // tile row 0..79
    const float w = Wm[(size_t)o * CIN + c];
    const unsigned hi = bf16_rne(w);
    const float    fl = w - __uint_as_float(hi << 16);
    const unsigned lo = bf16_rne(fl);
    const int kc = c >> 5, cc = c & 31;
    char* base = ws + (size_t)((g * 8 + kc) * 2) * TILE_B + p * 80 + cc * 2;
    *(unsigned short*)(base)          = (unsigned short)hi;
    *(unsigned short*)(base + TILE_B) = (unsigned short)lo;
}

// ---------------------------------------------------------------------------
__global__ __launch_bounds__(512) void zero_mask_kernel(float* __restrict__ out) {
    out[threadIdx.x] = 0.0f;
}

// ---------------------------------------------------------------------------
// Split-bf16 MFMA GEMM (640x256 @ 256x128-tile) + lane-local softmax, then
// LDS-transposed coalesced writeback (float4, 512B contiguity per half-wave).
__global__ __launch_bounds__(256, 2) void fused_main(const float* __restrict__ x,
                                                     const char* __restrict__ wimg,
                                                     const float* __restrict__ bvec,
                                                     float* __restrict__ out)
{
    __shared__ __align__(16) char atile[2][2][TILE_B];   // 32 KB [buf][hi/lo]
    __shared__ float pout[72 * PSTRIDE];                 // 38 KB softmax staging
    __shared__ float bsh[640];

    const int tid  = threadIdx.x;
    const int wave = tid >> 6, lane = tid & 63;
    const int q    = lane >> 4, m = lane & 15;
    const int b    = blockIdx.x >> 7;
    const int hw0  = (blockIdx.x & 127) * HWTILE;

    for (int i = tid; i < 640; i += 256) bsh[i] = bvec[i];

    // ---- B fragments: x[c][hw], lane holds 8 consecutive c; split hi/lo ----
    bf16x8 Bhi[2][8], Blo[2][8];
    const float* xb = x + (size_t)b * CIN * HW + hw0 + wave * 32 + m;
    #pragma unroll
    for (int t = 0; t < 2; ++t)
        #pragma unroll
        for (int kc = 0; kc < 8; ++kc) {
            float f[8];
            #pragma unroll
            for (int i = 0; i < 8; ++i)
                f[i] = xb[t * 16 + (size_t)(kc * 32 + q * 8 + i) * HW];
            union { unsigned u[4]; bf16x8 v; } uh, ul;
            #pragma unroll
            for (int jj = 0; jj < 4; ++jj) {
                const unsigned h0 = bf16_rne(f[2*jj]), h1 = bf16_rne(f[2*jj+1]);
                const float r0 = f[2*jj]   - __uint_as_float(h0 << 16);
                const float r1 = f[2*jj+1] - __uint_as_float(h1 << 16);
                uh.u[jj] = h0 | (h1 << 16);
                ul.u[jj] = bf16_rne(r0) | (bf16_rne(r1) << 16);
            }
            Bhi[t][kc] = uh.v; Blo[t][kc] = ul.v;
        }
    __syncthreads();

#define STAGE(tile, buf) do {                                                  \
    const char* _s = wimg + (size_t)((tile) * 2) * TILE_B;                     \
    gload_lds16(_s + tid * 16,                 &atile[buf][0][tid * 16]);      \
    gload_lds16(_s + 4096 + tid * 16,          &atile[buf][0][4096 + tid*16]); \
    gload_lds16(_s + TILE_B + tid * 16,        &atile[buf][1][tid * 16]);      \
    gload_lds16(_s + TILE_B + 4096 + tid * 16, &atile[buf][1][4096 + tid*16]); \
} while (0)

    STAGE(0, 0);
    #pragma unroll 1
    for (int g = 0; g < 8; ++g) {
        f32x4 acc[5][2];
        #pragma unroll
        for (int ot = 0; ot < 5; ++ot)
            #pragma unroll
            for (int t = 0; t < 2; ++t) acc[ot][t] = (f32x4){0.f, 0.f, 0.f, 0.f};

        #pragma unroll
        for (int kc = 0; kc < 8; ++kc) {
            const int cur = kc & 1;
            if (kc < 7)     STAGE(g * 8 + kc + 1, cur ^ 1);
            else if (g < 7) STAGE((g + 1) * 8,    cur ^ 1);   // prefetch next group
            // FIFO-counted waits: only drain what we must.
            // kc==0 (g>0): [prefetch(4), atomics(2), stores(9), stage(4)] out-
            // standing -> vmcnt(13) retires exactly prefetch+atomics, leaves
            // the 9 epilogue stores + new stage in flight.
            if (g == 7 && kc == 7)      asm volatile("s_waitcnt vmcnt(0)" ::: "memory");
            else if (kc == 0 && g > 0)  asm volatile("s_waitcnt vmcnt(13)" ::: "memory");
            else                        asm volatile("s_waitcnt vmcnt(4)" ::: "memory");
            __builtin_amdgcn_s_barrier();

            const char* ahi = &atile[cur][0][m * 80 + q * 16];
            const char* alo = &atile[cur][1][m * 80 + q * 16];
            #pragma unroll
            for (int ot = 0; ot < 5; ++ot) {
                const bf16x8 Ah = *(const bf16x8*)(ahi + ot * 1280);
                const bf16x8 Al = *(const bf16x8*)(alo + ot * 1280);
                #pragma unroll
                for (int t = 0; t < 2; ++t) {
                    acc[ot][t] = __builtin_amdgcn_mfma_f32_16x16x32_bf16(Ah, Bhi[t][kc], acc[ot][t], 0, 0, 0);
                    acc[ot][t] = __builtin_amdgcn_mfma_f32_16x16x32_bf16(Ah, Blo[t][kc], acc[ot][t], 0, 0, 0);
                    acc[ot][t] = __builtin_amdgcn_mfma_f32_16x16x32_bf16(Al, Bhi[t][kc], acc[ot][t], 0, 0, 0);
                }
            }
            asm volatile("s_waitcnt lgkmcnt(0)" ::: "memory");
            __builtin_amdgcn_s_barrier();
        }

        // ---- lane-local epilogue: lane owns mids q*2+mi at hw wave*32+t*16+m.
        //      raw(idx) = acc[idx>>2][t][idx&3]; pout row = jj*8 + lmid.
        #pragma unroll
        for (int mi = 0; mi < 2; ++mi) {
            const int lmid = q * 2 + mi;
            const int gmid = g * 8 + lmid;
            const int i0 = mi * 10;
            float s = acc[i0 >> 2][0][i0 & 3] + acc[i0 >> 2][1][i0 & 3];
            s += __shfl_xor(s, 1); s += __shfl_xor(s, 2);
            s += __shfl_xor(s, 4); s += __shfl_xor(s, 8);
            if (m == 0) atomicAdd(&out[b * NMID + gmid], s);
            float bj[9];
            #pragma unroll
            for (int jj = 0; jj < 9; ++jj) bj[jj] = bsh[NMID + gmid * 9 + jj];
            #pragma unroll
            for (int t = 0; t < 2; ++t) {
                float p[9];
                #pragma unroll
                for (int jj = 0; jj < 9; ++jj) {
                    const int idx = i0 + 1 + jj;
                    p[jj] = acc[idx >> 2][t][idx & 3] + bj[jj];
                }
                float mx = p[0];
                #pragma unroll
                for (int jj = 1; jj < 9; ++jj) mx = fmaxf(mx, p[jj]);
                float ss = 0.f;
                #pragma unroll
                for (int jj = 0; jj < 9; ++jj) { p[jj] = __expf(p[jj] - mx); ss += p[jj]; }
                const float rs = 1.0f / ss;
                const int hwl = wave * 32 + t * 16 + m;
                #pragma unroll
                for (int jj = 0; jj < 9; ++jj)
                    pout[(jj * 8 + lmid) * PSTRIDE + hwl] = p[jj] * rs;
            }
        }
        __syncthreads();
        // ---- coalesced writeback: 72 rows x 128 cols as float4 ----
        const int rbase = tid >> 5;            // 0..7  -> lmid
        const int colb  = (tid & 31) * 4;      // 0..124
        #pragma unroll
        for (int r9 = 0; r9 < 9; ++r9) {       // -> jj
            const float4 v = *(const float4*)&pout[(r9 * 8 + rbase) * PSTRIDE + colb];
            *(float4*)(out + NORM_OFF
                       + ((size_t)((b * NMID + g * 8 + rbase) * 9 + r9)) * HW
                       + hw0 + colb) = v;
        }
        // next group's pout writes are behind the k-loop's barriers -> safe
    }
#undef STAGE
}

// ---------------------------------------------------------------------------
// One block, 8 waves; wave b handles batch b. Sigmoid of means (+score bias),
// stable top-k (desc value, tie -> lower index), mask, k, indices.
__global__ __launch_bounds__(512) void finalize_kernel(float* __restrict__ out,
                                                       const float* __restrict__ bvec,
                                                       int k)
{
    const int tid  = threadIdx.x;
    const int b    = tid >> 6;
    const int lane = tid & 63;
    const float sum = out[b * NMID + lane];
    const float sv  = 1.0f / (1.0f + __expf(-(sum * (1.0f / 16384.0f) + bvec[lane])));
    float val      = sv;
    float selected = 0.0f;
    for (int t = 0; t < k; ++t) {
        float bvv = val;
        int   bi  = lane;
        #pragma unroll
        for (int off = 32; off >= 1; off >>= 1) {
            const float ov = __shfl_xor(bvv, off);
            const int   oi = __shfl_xor(bi, off);
            if (ov > bvv || (ov == bvv && oi < bi)) { bvv = ov; bi = oi; }
        }
        if (lane == bi) { val = -INFINITY; selected = 1.0f; }
        if (lane == 0) out[IDX_OFF + b * k + t] = (float)bi;
    }
    out[b * NMID + lane] = selected;            // overwrite sums with mask
    if (tid == 0) out[K_OFF] = (float)k;
}

// ---------------------------------------------------------------------------
extern "C" void kernel_launch(void* const* d_in, const int* in_sizes, int n_in,
                              void* d_out, int out_size, void* d_ws, size_t ws_size,
                              hipStream_t stream)
{
    const float* x    = (const float*)d_in[0];
    const float* Wm   = (const float*)d_in[1];
    const float* bvec = (const float*)d_in[2];
    float* out = (float*)d_out;
    char*  ws  = (char*)d_ws;           // 64 tiles x 2 parts x 8192 B = 1 MB

    // out_size = 512 (mask) + 75497472 (norm_kernels) + 1 (k) + 8*k (indices)
    const int k = (out_size - IDX_OFF) / 8;

    prep_w<<<640, 256, 0, stream>>>(Wm, ws);
    zero_mask_kernel<<<1, 512, 0, stream>>>(out);
    fused_main<<<8 * (HW / HWTILE), 256, 0, stream>>>(x, ws, bvec, out);
    finalize_kernel<<<1, 512, 0, stream>>>(out, bvec, k);
}

// Round 6
// 239.385 us; speedup vs baseline: 1.0745x; 1.0745x over previous
//
#include <hip/hip_runtime.h>
#include <math.h>

constexpr int CIN      = 256;
constexpr int HW       = 16384;       // 128*128
constexpr int NMID     = 64;
constexpr int HWTILE   = 128;         // spatial positions per block (4 waves x 32)
constexpr int TILE_B   = 8192;        // padded A-tile image (80 rows x 80B)
constexpr int NORM_OFF = 512;         // mask (8*64) floats first
constexpr int K_OFF    = 75497984;    // 512 + 8*64*9*16384
constexpr int IDX_OFF  = 75497985;

typedef __attribute__((ext_vector_type(8))) short bf16x8;   // 8 bf16 = 4 VGPR
typedef __attribute__((ext_vector_type(4))) float f32x4;

__device__ __forceinline__ unsigned bf16_rne(float f) {
    unsigned u = __float_as_uint(f);
    return (u + 0x7fffu + ((u >> 16) & 1u)) >> 16;          // bf16 bits, RNE
}

__device__ __forceinline__ void gload_lds16(const void* gsrc, void* ldst) {
    __builtin_amdgcn_global_load_lds(
        (const __attribute__((address_space(1))) void*)gsrc,
        (__attribute__((address_space(3))) void*)ldst, 16, 0, 0);
}

// ---------------------------------------------------------------------------
// Repack W into MFMA A-fragment image, split bf16 hi/lo, with a row permutation
// chosen so each mid's 10 rows (score + 9 taps) land in ONE lane's D-fragments:
// D row-in-block = q*4+reg  =>  position p = (idx/4)*16 + q*4 + idx%4, where
// q = (mid&7)>>1, idx = (mid&1)*10 + j.  Tile (g*8+kc, part): 80 rows x 32 c.
__global__ __launch_bounds__(256) void prep_w(const float* __restrict__ Wm,
                                              char* __restrict__ ws)
{
    const int o = blockIdx.x;         // original W row 0..639
    const int c = threadIdx.x;        // 0..255
    int mid, j;
    if (o < NMID) { mid = o; j = 0; }
    else          { mid = (o - NMID) / 9; j = 1 + (o - NMID) % 9; }
    const int g  = mid >> 3, ml = mid & 7, q = ml >> 1, mi = ml & 1;
    const int idx = mi * 10 + j;
    const int p   = (idx >> 2) * 16 + q * 4 + (idx & 3);    // tile row 0..79
    const float w = Wm[(size_t)o * CIN + c];
    const unsigned hi = bf16_rne(w);
    const float    fl = w - __uint_as_float(hi << 16);
    const unsigned lo = bf16_rne(fl);
    const int kc = c >> 5, cc = c & 31;
    char* base = ws + (size_t)((g * 8 + kc) * 2) * TILE_B + p * 80 + cc * 2;
    *(unsigned short*)(base)          = (unsigned short)hi;
    *(unsigned short*)(base + TILE_B) = (unsigned short)lo;
}

// ---------------------------------------------------------------------------
__global__ __launch_bounds__(512) void zero_mask_kernel(float* __restrict__ out) {
    out[threadIdx.x] = 0.0f;
}

// ---------------------------------------------------------------------------
// Split-bf16 MFMA GEMM (640x256 @ 256x128-tile) + lane-local softmax epilogue.
// 4 waves; wave w owns hw [hw0+32w, hw0+32w+32) as two 16-col tiles (nh=2).
// B-frags resident in registers; A streamed through a 3-buffer LDS pipeline
// with 2-step prefetch distance and FIFO-counted vmcnt (never drain stores).
__global__ __launch_bounds__(256, 2) void fused_main(const float* __restrict__ x,
                                                     const char* __restrict__ wimg,
                                                     const float* __restrict__ bvec,
                                                     float* __restrict__ out)
{
    __shared__ __align__(16) char atile[3][2][TILE_B];   // 48 KB [buf][hi/lo]
    __shared__ float bsh[640];

    const int tid  = threadIdx.x;
    const int wave = tid >> 6, lane = tid & 63;
    const int q    = lane >> 4, m = lane & 15;
    const int b    = blockIdx.x >> 7;
    const int hw0  = (blockIdx.x & 127) * HWTILE;

#define STAGE(tile, buf) do {                                                  \
    const char* _s = wimg + (size_t)((tile) * 2) * TILE_B;                     \
    char* _d = &atile[buf][0][0];                                              \
    gload_lds16(_s + tid * 16,                 _d + tid * 16);                 \
    gload_lds16(_s + 4096 + tid * 16,          _d + 4096 + tid * 16);          \
    gload_lds16(_s + TILE_B + tid * 16,        _d + TILE_B + tid * 16);        \
    gload_lds16(_s + TILE_B + 4096 + tid * 16, _d + TILE_B + 4096 + tid * 16); \
} while (0)

    // ---- issue tiles 0,1 immediately; latency hides under B-build ----
    STAGE(0, 0);
    STAGE(1, 1);

    // ---- B fragments: x[c][hw], lane holds 8 consecutive c; split hi/lo ----
    bf16x8 Bhi[2][8], Blo[2][8];
    const float* xb = x + (size_t)b * CIN * HW + hw0 + wave * 32 + m;
    #pragma unroll
    for (int t = 0; t < 2; ++t)
        #pragma unroll
        for (int kc = 0; kc < 8; ++kc) {
            float f[8];
            #pragma unroll
            for (int i = 0; i < 8; ++i)
                f[i] = xb[t * 16 + (size_t)(kc * 32 + q * 8 + i) * HW];
            union { unsigned u[4]; bf16x8 v; } uh, ul;
            #pragma unroll
            for (int jj = 0; jj < 4; ++jj) {
                const unsigned h0 = bf16_rne(f[2*jj]), h1 = bf16_rne(f[2*jj+1]);
                const float r0 = f[2*jj]   - __uint_as_float(h0 << 16);
                const float r1 = f[2*jj+1] - __uint_as_float(h1 << 16);
                uh.u[jj] = h0 | (h1 << 16);
                ul.u[jj] = bf16_rne(r0) | (bf16_rne(r1) << 16);
            }
            Bhi[t][kc] = uh.v; Blo[t][kc] = ul.v;
        }
    for (int i = tid; i < 640; i += 256) bsh[i] = bvec[i];
    asm volatile("s_waitcnt lgkmcnt(0)" ::: "memory");
    __builtin_amdgcn_s_barrier();

    int cur = 0;                        // LDS buffer holding tile t
    #pragma unroll 1
    for (int g = 0; g < 8; ++g) {
        f32x4 acc[5][2];
        #pragma unroll
        for (int ot = 0; ot < 5; ++ot)
            #pragma unroll
            for (int t = 0; t < 2; ++t) acc[ot][t] = (f32x4){0.f, 0.f, 0.f, 0.f};

        #pragma unroll
        for (int kc = 0; kc < 8; ++kc) {
            const int t  = g * 8 + kc;
            const int nb = (cur >= 1) ? cur - 1 : 2;     // (cur+2)%3
            if (t <= 61) STAGE(t + 2, nb);
            // FIFO-counted waits (vmcnt retires in issue order):
            //   steady: [stage t+1 (4), stage t+2 (4)] in flight -> vmcnt(8)
            //   after epilogue: + 38 stores/atomics -> vmcnt(46)
            //   tail: t=62 -> vmcnt(4); t=63 -> vmcnt(0)
            if (kc == 0) {
                if (g > 0) asm volatile("s_waitcnt vmcnt(46)" ::: "memory");
                else       asm volatile("s_waitcnt vmcnt(8)"  ::: "memory");
            } else if (kc == 6) {
                if (g == 7) asm volatile("s_waitcnt vmcnt(4)" ::: "memory");
                else        asm volatile("s_waitcnt vmcnt(8)" ::: "memory");
            } else if (kc == 7) {
                if (g == 7) asm volatile("s_waitcnt vmcnt(0)" ::: "memory");
                else        asm volatile("s_waitcnt vmcnt(8)" ::: "memory");
            } else {
                asm volatile("s_waitcnt vmcnt(8)" ::: "memory");
            }
            __builtin_amdgcn_s_barrier();

            const char* ahi = &atile[cur][0][m * 80 + q * 16];
            const char* alo = &atile[cur][1][m * 80 + q * 16];
            __builtin_amdgcn_s_setprio(1);
            #pragma unroll
            for (int ot = 0; ot < 5; ++ot) {
                const bf16x8 Ah = *(const bf16x8*)(ahi + ot * 1280);
                const bf16x8 Al = *(const bf16x8*)(alo + ot * 1280);
                #pragma unroll
                for (int t2 = 0; t2 < 2; ++t2) {
                    acc[ot][t2] = __builtin_amdgcn_mfma_f32_16x16x32_bf16(Ah, Bhi[t2][kc], acc[ot][t2], 0, 0, 0);
                    acc[ot][t2] = __builtin_amdgcn_mfma_f32_16x16x32_bf16(Ah, Blo[t2][kc], acc[ot][t2], 0, 0, 0);
                    acc[ot][t2] = __builtin_amdgcn_mfma_f32_16x16x32_bf16(Al, Bhi[t2][kc], acc[ot][t2], 0, 0, 0);
                }
            }
            __builtin_amdgcn_s_setprio(0);

            // ---- epilogue at kc==7, BEFORE the phase barrier (waves drift) ----
            if (kc == 7) {
                #pragma unroll
                for (int mi = 0; mi < 2; ++mi) {
                    const int gmid = g * 8 + q * 2 + mi;
                    const int i0 = mi * 10;
                    float s = acc[i0 >> 2][0][i0 & 3] + acc[i0 >> 2][1][i0 & 3];
                    s += __shfl_xor(s, 1); s += __shfl_xor(s, 2);
                    s += __shfl_xor(s, 4); s += __shfl_xor(s, 8);
                    if (m == 0) atomicAdd(&out[b * NMID + gmid], s);
                    float bj[9];
                    #pragma unroll
                    for (int jj = 0; jj < 9; ++jj) bj[jj] = bsh[NMID + gmid * 9 + jj];
                    #pragma unroll
                    for (int t2 = 0; t2 < 2; ++t2) {
                        float p[9];
                        #pragma unroll
                        for (int jj = 0; jj < 9; ++jj) {
                            const int idx = i0 + 1 + jj;
                            p[jj] = acc[idx >> 2][t2][idx & 3] + bj[jj];
                        }
                        float mx = p[0];
                        #pragma unroll
                        for (int jj = 1; jj < 9; ++jj) mx = fmaxf(mx, p[jj]);
                        float ss = 0.f;
                        #pragma unroll
                        for (int jj = 0; jj < 9; ++jj) { p[jj] = __expf(p[jj] - mx); ss += p[jj]; }
                        const float rs = 1.0f / ss;
                        float* ob = out + NORM_OFF
                                  + ((size_t)((b * NMID + gmid) * 9)) * HW
                                  + hw0 + wave * 32 + t2 * 16 + m;
                        #pragma unroll
                        for (int jj = 0; jj < 9; ++jj)
                            ob[(size_t)jj * HW] = p[jj] * rs;
                    }
                }
            }
            asm volatile("s_waitcnt lgkmcnt(0)" ::: "memory");
            __builtin_amdgcn_s_barrier();
            cur = (cur == 2) ? 0 : cur + 1;
        }
    }
#undef STAGE
}

// ---------------------------------------------------------------------------
// One block, 8 waves; wave b handles batch b. Sigmoid of means (+score bias),
// stable top-k (desc value, tie -> lower index), mask, k, indices.
__global__ __launch_bounds__(512) void finalize_kernel(float* __restrict__ out,
                                                       const float* __restrict__ bvec,
                                                       int k)
{
    const int tid  = threadIdx.x;
    const int b    = tid >> 6;
    const int lane = tid & 63;
    const float sum = out[b * NMID + lane];
    const float sv  = 1.0f / (1.0f + __expf(-(sum * (1.0f / 16384.0f) + bvec[lane])));
    float val      = sv;
    float selected = 0.0f;
    for (int t = 0; t < k; ++t) {
        float bvv = val;
        int   bi  = lane;
        #pragma unroll
        for (int off = 32; off >= 1; off >>= 1) {
            const float ov = __shfl_xor(bvv, off);
            const int   oi = __shfl_xor(bi, off);
            if (ov > bvv || (ov == bvv && oi < bi)) { bvv = ov; bi = oi; }
        }
        if (lane == bi) { val = -INFINITY; selected = 1.0f; }
        if (lane == 0) out[IDX_OFF + b * k + t] = (float)bi;
    }
    out[b * NMID + lane] = selected;            // overwrite sums with mask
    if (tid == 0) out[K_OFF] = (float)k;
}

// ---------------------------------------------------------------------------
extern "C" void kernel_launch(void* const* d_in, const int* in_sizes, int n_in,
                              void* d_out, int out_size, void* d_ws, size_t ws_size,
                              hipStream_t stream)
{
    const float* x    = (const float*)d_in[0];
    const float* Wm   = (const float*)d_in[1];
    const float* bvec = (const float*)d_in[2];
    float* out = (float*)d_out;
    char*  ws  = (char*)d_ws;           // 64 tiles x 2 parts x 8192 B = 1 MB

    // out_size = 512 (mask) + 75497472 (norm_kernels) + 1 (k) + 8*k (indices)
    const int k = (out_size - IDX_OFF) / 8;

    prep_w<<<640, 256, 0, stream>>>(Wm, ws);
    zero_mask_kernel<<<1, 512, 0, stream>>>(out);
    fused_main<<<8 * (HW / HWTILE), 256, 0, stream>>>(x, ws, bvec, out);
    finalize_kernel<<<1, 512, 0, stream>>>(out, bvec, k);
}